// Round 7
// baseline (243.991 us; speedup 1.0000x reference)
//
#include <hip/hip_runtime.h>
#include <hip/hip_bf16.h>
#include <math.h>

typedef __attribute__((ext_vector_type(8)))  short short8;
typedef __attribute__((ext_vector_type(16))) float f32x16;

#define Bc    2
#define Hc    16
#define Lc    2048
#define Dc    128
#define QBLK  128
#define KBLK  64
#define LOG2E 1.4426950408889634f
#define SCALE 0.08838834764831845f           // 1/sqrt(128)
#define SCL2  (SCALE * LOG2E)                // log2-domain Q scale

// workspace layout
#define KB_OFF   0u
#define KB_BYTES (32u * 2048u * 128u * 2u)
#define VT_OFF   (KB_OFF + KB_BYTES)
#define VT_BYTES (32u * 2048u * 128u * 2u)
#define MB_OFF   (VT_OFF + VT_BYTES)

__device__ __forceinline__ unsigned pk2(float a, float b) {
    unsigned short ua = __builtin_bit_cast(unsigned short, __float2bfloat16(a));
    unsigned short ub = __builtin_bit_cast(unsigned short, __float2bfloat16(b));
    return (unsigned)ua | ((unsigned)ub << 16);
}
__device__ __forceinline__ unsigned short bf16b(float a) {
    return __builtin_bit_cast(unsigned short, __float2bfloat16(a));
}
__device__ __forceinline__ void gload_lds16(const void* g, void* l) {
    __builtin_amdgcn_global_load_lds(
        (const __attribute__((address_space(1))) unsigned int*)g,
        (__attribute__((address_space(3))) unsigned int*)l, 16, 0, 0);
}
__device__ __forceinline__ unsigned cvtpk(float lo, float hi) {
    unsigned r;
    asm("v_cvt_pk_bf16_f32 %0, %1, %2" : "=v"(r) : "v"(lo), "v"(hi));
    return r;
}

// ---- prepass 1: K fp32 -> bf16 ----
__global__ void conv_k_kernel(const float* __restrict__ k, unsigned short* __restrict__ kb) {
    int idx8 = blockIdx.x * 256 + threadIdx.x;
    size_t base = (size_t)idx8 * 8;
    float4 f0 = *(const float4*)(k + base);
    float4 f1 = *(const float4*)(k + base + 4);
    uint4 w;
    w.x = pk2(f0.x, f0.y); w.y = pk2(f0.z, f0.w);
    w.z = pk2(f1.x, f1.y); w.w = pk2(f1.z, f1.w);
    *(uint4*)(kb + base) = w;
}

// ---- prepass 2: V fp32 -> relu -> bf16 transposed per (b,h): [L][D] -> [D][L] ----
__global__ void transp_v_kernel(const float* __restrict__ v, unsigned short* __restrict__ vt) {
    __shared__ float t[32][33];
    int d0 = blockIdx.x * 32;
    int l0 = blockIdx.y * 32;
    int bh = blockIdx.z;
    int tx = threadIdx.x, ty = threadIdx.y;
    const float* src = v + (size_t)bh * Lc * Dc;
    unsigned short* dst = vt + (size_t)bh * Dc * Lc;
    #pragma unroll
    for (int i = 0; i < 4; ++i) {
        int row = ty * 4 + i;
        t[row][tx] = fmaxf(src[(size_t)(l0 + row) * Dc + d0 + tx], 0.f);
    }
    __syncthreads();
    #pragma unroll
    for (int i = 0; i < 4; ++i) {
        int drow = ty * 4 + i;
        dst[(size_t)(d0 + drow) * Lc + l0 + tx] = bf16b(t[tx][drow]);
    }
}

// ---- prepass 3: mask int32 -> transposed bitmask  mbT[b][ktw][l] ----
__global__ void mask_pack_kernel(const int* __restrict__ mask, unsigned long long* __restrict__ mb) {
    int tid  = threadIdx.x;
    int wv   = blockIdx.x * 4 + (tid >> 6);   // word over (b, l, ktw)
    int lane = tid & 63;
    int b    = wv >> 16;
    int l    = (wv >> 5) & 2047;
    int ktw  = wv & 31;
    int m = mask[(((size_t)(b * 2048 + l)) << 11) + ktw * 64 + lane];
    unsigned long long bal = __ballot(m != 0);
    if (lane == 0) mb[(((size_t)(b * 32 + ktw)) << 11) + l] = bal;
}

// ---- main: 8-wave (4 q-groups x 2 k-halves) 32x32 swapped-QK^T, fixed-shift softmax ----
__global__ __launch_bounds__(512, 4) void rev_attn_kernel(
    const float* __restrict__ q,
    const unsigned short* __restrict__ kb,
    const unsigned short* __restrict__ vt,
    const unsigned long long* __restrict__ mb,
    float* __restrict__ out)
{
    // LDS: Kbuf0 @0, Kbuf1 @16384, Vbuf0 @32768, Vbuf1 @49152
    // epilogue: scr [4 qg][32 d][32 q] f32 @0 (16 KB), lsum [4 qg][32 q] @16384
    __shared__ __align__(16) char smem[65536];

    const int tid  = threadIdx.x;
    const int w    = tid >> 6;          // 0..7
    const int lane = tid & 63;
    const int l31  = lane & 31;
    const int hi   = lane >> 5;
    const int qg   = w >> 1;            // 0..3: q-subblock
    const int kh   = w & 1;             // 0..1: k-half of each tile
    const int bh   = blockIdx.y;
    const int b    = bh >> 4;
    const int qb   = blockIdx.x * QBLK;
    const int qrow = qb + qg * 32 + l31;

    const float*              qp = q  + (size_t)bh * Lc * Dc;
    const unsigned short*     kp = kb + (size_t)bh * Lc * Dc;
    const unsigned short*     vp = vt + (size_t)bh * Dc * Lc;
    const unsigned long long* mp = mb + ((size_t)b << 16);       // [32 ktw][2048 l]
    float*                    op = out + (size_t)bh * Lc * Dc;

    // ---- Q B-frags (log2-domain pre-scale): lane holds Q[qrow][c*16 + hi*8 + j] ----
    short8 qf[8];
    {
        const float* qr0 = qp + (size_t)qrow * Dc + hi * 8;
        #pragma unroll
        for (int c = 0; c < 8; ++c) {
            const float* src = qr0 + c * 16;
            #pragma unroll
            for (int j = 0; j < 8; ++j)
                qf[c][j] = (short)bf16b(src[j] * SCL2);
        }
    }

    f32x16 o0 = (f32x16)0.f, o1 = (f32x16)0.f, o2 = (f32x16)0.f, o3 = (f32x16)0.f;
    float lrun = 0.f;

    // ---- staging: 1024 K chunks + 1024 V chunks of 16B; 512 threads -> 2+2 each ----
    #define STAGE(buf, kt_) do {                                                   \
        char* Kdst = smem + (buf) * 16384;                                         \
        char* Vdst = smem + 32768 + (buf) * 16384;                                 \
        _Pragma("unroll")                                                          \
        for (int p = 0; p < 2; ++p) {                                              \
            int l   = p * 512 + tid;                                               \
            int row = l >> 4, cl = l & 15;                                         \
            int s_  = cl ^ (row & 15);                                             \
            gload_lds16(kp + (size_t)((kt_) + row) * Dc + s_ * 8, Kdst + l * 16);  \
            int ds_ = row + ((s_ >> 3) << 6);                                      \
            int ko_ = (s_ & 7) * 8;                                                \
            gload_lds16(vp + (size_t)ds_ * Lc + (kt_) + ko_, Vdst + l * 16);       \
        }                                                                          \
    } while (0)

    int cur = 0;
    STAGE(0, 0);
    __syncthreads();

    const int r0 = kh * 32 + l31;       // K-tile row this lane reads (A-frag)
    for (int kt = 0; kt < Lc; kt += KBLK) {
        if (kt + KBLK < Lc) STAGE(cur ^ 1, kt + KBLK);
        unsigned long long mw = mp[((size_t)(kt >> 6) << 11) + qrow];
        const char* Kb = smem + cur * 16384;
        const char* Vb = smem + 32768 + cur * 16384;

        // ---- QK^T (swapped): S^T[kh-half rows][q], col=q=l31 ----
        f32x16 s = (f32x16)0.f;
        __builtin_amdgcn_s_setprio(1);
        #pragma unroll
        for (int c = 0; c < 8; ++c) {
            short8 kf = *(const short8*)(Kb + r0 * 256 + ((((c << 1) | hi)) ^ (r0 & 15)) * 16);
            s = __builtin_amdgcn_mfma_f32_32x32x16_bf16(kf, qf[c], s, 0, 0, 0);
        }
        __builtin_amdgcn_s_setprio(0);

        // ---- fixed-shift softmax numerator: P = exp2(S_log2), mask-zero ----
        unsigned mh = (unsigned)(mw >> (kh * 32));
        unsigned m0 = mh >> (4 * hi);
        #pragma unroll
        for (int r = 0; r < 16; ++r) {
            const int cs = (r & 3) + 8 * (r >> 2);
            float e = exp2f(s[r]);
            s[r] = ((m0 >> cs) & 1u) ? e : 0.f;
        }

        // ---- tree-sum denominator (this k-half) ----
        {
            float a0 = (s[0] + s[1]) + (s[2] + s[3]);
            float a1 = (s[4] + s[5]) + (s[6] + s[7]);
            float a2 = (s[8] + s[9]) + (s[10] + s[11]);
            float a3 = (s[12] + s[13]) + (s[14] + s[15]);
            float rs = (a0 + a1) + (a2 + a3);
            rs += __shfl_xor(rs, 32);
            lrun += rs;
        }

        // ---- P^T -> bf16 B-frags via cvt_pk + permlane32_swap ----
        // pa[ks]: lane holds P[qrow][kh*32 + ks*16 + hi*8 + j]
        short8 pa[2];
        {
            union { unsigned u[4]; short8 v; } t0, t1;
            unsigned a, a2, bb, b2;
            a  = cvtpk(s[0], s[1]);  a2 = cvtpk(s[2], s[3]);
            bb = cvtpk(s[4], s[5]);  b2 = cvtpk(s[6], s[7]);
            asm volatile("v_permlane32_swap_b32 %0, %1" : "+v"(a),  "+v"(bb));
            asm volatile("v_permlane32_swap_b32 %0, %1" : "+v"(a2), "+v"(b2));
            t0.u[0] = a; t0.u[1] = a2; t0.u[2] = bb; t0.u[3] = b2;
            a  = cvtpk(s[8],  s[9]);  a2 = cvtpk(s[10], s[11]);
            bb = cvtpk(s[12], s[13]); b2 = cvtpk(s[14], s[15]);
            asm volatile("v_permlane32_swap_b32 %0, %1" : "+v"(a),  "+v"(bb));
            asm volatile("v_permlane32_swap_b32 %0, %1" : "+v"(a2), "+v"(b2));
            t1.u[0] = a; t1.u[1] = a2; t1.u[2] = bb; t1.u[3] = b2;
            pa[0] = t0.v; pa[1] = t1.v;
        }

        // ---- PV (swapped): O^T[d][q] += V^T * P^T over this wave's k-half ----
        __builtin_amdgcn_s_setprio(1);
        #pragma unroll
        for (int dt = 0; dt < 4; ++dt) {
            int vrow = (dt & 1) * 32 + l31;
            int hs   = dt >> 1;
            int vswz = vrow & 15;
            f32x16 acc = (dt == 0) ? o0 : (dt == 1) ? o1 : (dt == 2) ? o2 : o3;
            #pragma unroll
            for (int ks = 0; ks < 2; ++ks) {
                int colsel = (hs << 3) | (kh << 2) | (ks << 1) | hi;
                short8 vf = *(const short8*)(Vb + vrow * 256 + ((colsel ^ vswz) * 16));
                acc = __builtin_amdgcn_mfma_f32_32x32x16_bf16(vf, pa[ks], acc, 0, 0, 0);
            }
            if (dt == 0) o0 = acc; else if (dt == 1) o1 = acc; else if (dt == 2) o2 = acc; else o3 = acc;
        }
        __builtin_amdgcn_s_setprio(0);

        __syncthreads();
        cur ^= 1;
    }

    // ---- epilogue: merge k-half wave pairs via LDS, normalize, coalesced store ----
    float* scr = (float*)(smem + qg * 4096);          // [32 d][32 q] f32 per qg
    float* lsp = (float*)(smem + 16384 + qg * 128);   // [32 q] f32 per qg
    if (kh == 1 && hi == 0) lsp[l31] = lrun;
    float inv = 0.f;
    const int qq2 = kh * 16 + (lane >> 2);
    const int dh2 = (lane & 3) * 8;
    #pragma unroll
    for (int dt = 0; dt < 4; ++dt) {
        const f32x16& oo = (dt == 0) ? o0 : (dt == 1) ? o1 : (dt == 2) ? o2 : o3;
        if (kh == 1) {
            #pragma unroll
            for (int r = 0; r < 16; ++r)
                scr[((r & 3) + 8 * (r >> 2) + 4 * hi) * 32 + l31] = oo[r];
        }
        __syncthreads();
        if (kh == 0) {
            if (dt == 0) inv = 1.0f / (lrun + lsp[l31]);
            #pragma unroll
            for (int r = 0; r < 16; ++r) {
                int ix = ((r & 3) + 8 * (r >> 2) + 4 * hi) * 32 + l31;
                scr[ix] = (scr[ix] + oo[r]) * inv;
            }
        }
        __syncthreads();
        float t[8];
        #pragma unroll
        for (int c2 = 0; c2 < 8; ++c2)
            t[c2] = scr[(dh2 + c2) * 32 + qq2];
        float* od = op + (size_t)(qb + qg * 32 + qq2) * Dc + dt * 32 + dh2;
        float4 f4a, f4b;
        f4a.x = t[0]; f4a.y = t[1]; f4a.z = t[2]; f4a.w = t[3];
        f4b.x = t[4]; f4b.y = t[5]; f4b.z = t[6]; f4b.w = t[7];
        *(float4*)(od)     = f4a;
        *(float4*)(od + 4) = f4b;
        if (dt < 3) __syncthreads();
    }
}

extern "C" void kernel_launch(void* const* d_in, const int* in_sizes, int n_in,
                              void* d_out, int out_size, void* d_ws, size_t ws_size,
                              hipStream_t stream) {
    const float* q    = (const float*)d_in[0];
    const float* k    = (const float*)d_in[1];
    const float* v    = (const float*)d_in[2];
    const int*   mask = (const int*)d_in[3];
    float*       out  = (float*)d_out;

    char* ws = (char*)d_ws;
    unsigned short*     kb  = (unsigned short*)(ws + KB_OFF);
    unsigned short*     vt  = (unsigned short*)(ws + VT_OFF);
    unsigned long long* mbp = (unsigned long long*)(ws + MB_OFF);

    hipLaunchKernelGGL(conv_k_kernel, dim3(4096), dim3(256), 0, stream, k, kb);
    hipLaunchKernelGGL(transp_v_kernel, dim3(4, 64, 32), dim3(32, 8), 0, stream, v, vt);
    hipLaunchKernelGGL(mask_pack_kernel, dim3(32768), dim3(256), 0, stream, mask, mbp);

    hipLaunchKernelGGL(rev_attn_kernel, dim3(Lc / QBLK, Bc * Hc), dim3(512), 0, stream,
                       q, kb, vt, mbp, out);
}

// Round 8
// 152.635 us; speedup vs baseline: 1.5985x; 1.5985x over previous
//
#include <hip/hip_runtime.h>
#include <hip/hip_bf16.h>
#include <math.h>

typedef __attribute__((ext_vector_type(8)))  short short8;
typedef __attribute__((ext_vector_type(16))) float f32x16;

#define Bc    2
#define Hc    16
#define Lc    2048
#define Dc    128
#define QBLK  64
#define KBLK  64
#define LOG2E 1.4426950408889634f
#define SCALE 0.08838834764831845f           // 1/sqrt(128)
#define SCL2  (SCALE * LOG2E)                // log2-domain Q scale

// workspace layout
#define KB_OFF   0u
#define KB_BYTES (32u * 2048u * 128u * 2u)
#define VT_OFF   (KB_OFF + KB_BYTES)
#define VT_BYTES (32u * 2048u * 128u * 2u)
#define MB_OFF   (VT_OFF + VT_BYTES)

__device__ __forceinline__ unsigned pk2(float a, float b) {
    unsigned short ua = __builtin_bit_cast(unsigned short, __float2bfloat16(a));
    unsigned short ub = __builtin_bit_cast(unsigned short, __float2bfloat16(b));
    return (unsigned)ua | ((unsigned)ub << 16);
}
__device__ __forceinline__ unsigned short bf16b(float a) {
    return __builtin_bit_cast(unsigned short, __float2bfloat16(a));
}
__device__ __forceinline__ void gload_lds16(const void* g, void* l) {
    __builtin_amdgcn_global_load_lds(
        (const __attribute__((address_space(1))) unsigned int*)g,
        (__attribute__((address_space(3))) unsigned int*)l, 16, 0, 0);
}
__device__ __forceinline__ unsigned cvtpk(float lo, float hi) {
    unsigned r;
    asm("v_cvt_pk_bf16_f32 %0, %1, %2" : "=v"(r) : "v"(lo), "v"(hi));
    return r;
}

// ---- prepass 1: K fp32 -> bf16 ----
__global__ void conv_k_kernel(const float* __restrict__ k, unsigned short* __restrict__ kb) {
    int idx8 = blockIdx.x * 256 + threadIdx.x;
    size_t base = (size_t)idx8 * 8;
    float4 f0 = *(const float4*)(k + base);
    float4 f1 = *(const float4*)(k + base + 4);
    uint4 w;
    w.x = pk2(f0.x, f0.y); w.y = pk2(f0.z, f0.w);
    w.z = pk2(f1.x, f1.y); w.w = pk2(f1.z, f1.w);
    *(uint4*)(kb + base) = w;
}

// ---- prepass 2: V fp32 -> relu -> bf16 transposed per (b,h): [L][D] -> [D][L] ----
__global__ void transp_v_kernel(const float* __restrict__ v, unsigned short* __restrict__ vt) {
    __shared__ float t[32][33];
    int d0 = blockIdx.x * 32;
    int l0 = blockIdx.y * 32;
    int bh = blockIdx.z;
    int tx = threadIdx.x, ty = threadIdx.y;
    const float* src = v + (size_t)bh * Lc * Dc;
    unsigned short* dst = vt + (size_t)bh * Dc * Lc;
    #pragma unroll
    for (int i = 0; i < 4; ++i) {
        int row = ty * 4 + i;
        t[row][tx] = fmaxf(src[(size_t)(l0 + row) * Dc + d0 + tx], 0.f);
    }
    __syncthreads();
    #pragma unroll
    for (int i = 0; i < 4; ++i) {
        int drow = ty * 4 + i;
        dst[(size_t)(d0 + drow) * Lc + l0 + tx] = bf16b(t[tx][drow]);
    }
}

// ---- prepass 3: mask int32 -> transposed bitmask  mbT[b][ktw][l] ----
__global__ void mask_pack_kernel(const int* __restrict__ mask, unsigned long long* __restrict__ mb) {
    int tid  = threadIdx.x;
    int wv   = blockIdx.x * 4 + (tid >> 6);   // word over (b, l, ktw)
    int lane = tid & 63;
    int b    = wv >> 16;
    int l    = (wv >> 5) & 2047;
    int ktw  = wv & 31;
    int m = mask[(((size_t)(b * 2048 + l)) << 11) + ktw * 64 + lane];
    unsigned long long bal = __ballot(m != 0);
    if (lane == 0) mb[(((size_t)(b * 32 + ktw)) << 11) + l] = bal;
}

// ---- main: 4-wave (2 q-groups x 2 k-halves), QBLK=64, single-buffer, 4 blocks/CU ----
__global__ __launch_bounds__(256, 2) void rev_attn_kernel(
    const float* __restrict__ q,
    const unsigned short* __restrict__ kb,
    const unsigned short* __restrict__ vt,
    const unsigned long long* __restrict__ mb,
    float* __restrict__ out)
{
    // LDS: K @0 (16 KB), V @16384 (16 KB). Epilogue aliases: scr[2 qg][32 d][32 q]
    // f32 @0 (8 KB), lsum[2 qg][32 q] @8192.
    __shared__ __align__(16) char smem[32768];

    const int tid  = threadIdx.x;
    const int w    = tid >> 6;          // 0..3
    const int lane = tid & 63;
    const int l31  = lane & 31;
    const int hi   = lane >> 5;
    const int qg   = w >> 1;            // 0..1: q-subblock
    const int kh   = w & 1;             // 0..1: k-half of each tile
    const int bh   = blockIdx.y;
    const int b    = bh >> 4;
    const int qb   = blockIdx.x * QBLK;
    const int qrow = qb + qg * 32 + l31;

    const float*              qp = q  + (size_t)bh * Lc * Dc;
    const unsigned short*     kp = kb + (size_t)bh * Lc * Dc;
    const unsigned short*     vp = vt + (size_t)bh * Dc * Lc;
    const unsigned long long* mp = mb + ((size_t)b << 16);       // [32 ktw][2048 l]
    float*                    op = out + (size_t)bh * Lc * Dc;

    // ---- Q B-frags (log2-domain pre-scale): lane holds Q[qrow][c*16 + hi*8 + j] ----
    short8 qf[8];
    {
        const float* qr0 = qp + (size_t)qrow * Dc + hi * 8;
        #pragma unroll
        for (int c = 0; c < 8; ++c) {
            const float* src = qr0 + c * 16;
            #pragma unroll
            for (int j = 0; j < 8; ++j)
                qf[c][j] = (short)bf16b(src[j] * SCL2);
        }
    }

    f32x16 o0 = (f32x16)0.f, o1 = (f32x16)0.f, o2 = (f32x16)0.f, o3 = (f32x16)0.f;
    float lrun = 0.f;

    // ---- staging: 1024 K chunks + 1024 V chunks of 16B; 256 threads -> 4+4 each ----
    #define STAGE(kt_) do {                                                        \
        char* Kdst = smem;                                                         \
        char* Vdst = smem + 16384;                                                 \
        _Pragma("unroll")                                                          \
        for (int p = 0; p < 4; ++p) {                                              \
            int l   = p * 256 + tid;                                               \
            int row = l >> 4, cl = l & 15;                                         \
            int s_  = cl ^ (row & 15);                                             \
            gload_lds16(kp + (size_t)((kt_) + row) * Dc + s_ * 8, Kdst + l * 16);  \
            int ds_ = row + ((s_ >> 3) << 6);                                      \
            int ko_ = (s_ & 7) * 8;                                                \
            gload_lds16(vp + (size_t)ds_ * Lc + (kt_) + ko_, Vdst + l * 16);       \
        }                                                                          \
    } while (0)

    const int r0 = kh * 32 + l31;       // K-tile row this lane reads (A-frag)
    const char* Kb = smem;
    const char* Vb = smem + 16384;

    for (int kt = 0; kt < Lc; kt += KBLK) {
        STAGE(kt);
        unsigned long long mw = mp[((size_t)(kt >> 6) << 11) + qrow];
        __syncthreads();                 // staging complete (vmcnt drained by barrier)

        // ---- QK^T (swapped): S^T[kh-half rows][q], col=q=l31 ----
        f32x16 s = (f32x16)0.f;
        __builtin_amdgcn_s_setprio(1);
        #pragma unroll
        for (int c = 0; c < 8; ++c) {
            short8 kf = *(const short8*)(Kb + r0 * 256 + ((((c << 1) | hi)) ^ (r0 & 15)) * 16);
            s = __builtin_amdgcn_mfma_f32_32x32x16_bf16(kf, qf[c], s, 0, 0, 0);
        }
        __builtin_amdgcn_s_setprio(0);

        // ---- fixed-shift softmax numerator: P = exp2(S_log2), mask-zero ----
        unsigned mh = (unsigned)(mw >> (kh * 32));
        unsigned m0 = mh >> (4 * hi);
        #pragma unroll
        for (int r = 0; r < 16; ++r) {
            const int cs = (r & 3) + 8 * (r >> 2);
            float e = exp2f(s[r]);
            s[r] = ((m0 >> cs) & 1u) ? e : 0.f;
        }

        // ---- tree-sum denominator (this k-half) ----
        {
            float a0 = (s[0] + s[1]) + (s[2] + s[3]);
            float a1 = (s[4] + s[5]) + (s[6] + s[7]);
            float a2 = (s[8] + s[9]) + (s[10] + s[11]);
            float a3 = (s[12] + s[13]) + (s[14] + s[15]);
            float rs = (a0 + a1) + (a2 + a3);
            rs += __shfl_xor(rs, 32);
            lrun += rs;
        }

        // ---- P^T -> bf16 B-frags via cvt_pk + permlane32_swap ----
        short8 pa[2];
        {
            union { unsigned u[4]; short8 v; } t0, t1;
            unsigned a, a2, bb, b2;
            a  = cvtpk(s[0], s[1]);  a2 = cvtpk(s[2], s[3]);
            bb = cvtpk(s[4], s[5]);  b2 = cvtpk(s[6], s[7]);
            asm volatile("v_permlane32_swap_b32 %0, %1" : "+v"(a),  "+v"(bb));
            asm volatile("v_permlane32_swap_b32 %0, %1" : "+v"(a2), "+v"(b2));
            t0.u[0] = a; t0.u[1] = a2; t0.u[2] = bb; t0.u[3] = b2;
            a  = cvtpk(s[8],  s[9]);  a2 = cvtpk(s[10], s[11]);
            bb = cvtpk(s[12], s[13]); b2 = cvtpk(s[14], s[15]);
            asm volatile("v_permlane32_swap_b32 %0, %1" : "+v"(a),  "+v"(bb));
            asm volatile("v_permlane32_swap_b32 %0, %1" : "+v"(a2), "+v"(b2));
            t1.u[0] = a; t1.u[1] = a2; t1.u[2] = bb; t1.u[3] = b2;
            pa[0] = t0.v; pa[1] = t1.v;
        }

        // ---- PV (swapped): O^T[d][q] += V^T * P^T over this wave's k-half ----
        __builtin_amdgcn_s_setprio(1);
        #pragma unroll
        for (int dt = 0; dt < 4; ++dt) {
            int vrow = (dt & 1) * 32 + l31;
            int hs   = dt >> 1;
            int vswz = vrow & 15;
            f32x16 acc = (dt == 0) ? o0 : (dt == 1) ? o1 : (dt == 2) ? o2 : o3;
            #pragma unroll
            for (int ks = 0; ks < 2; ++ks) {
                int colsel = (hs << 3) | (kh << 2) | (ks << 1) | hi;
                short8 vf = *(const short8*)(Vb + vrow * 256 + ((colsel ^ vswz) * 16));
                acc = __builtin_amdgcn_mfma_f32_32x32x16_bf16(vf, pa[ks], acc, 0, 0, 0);
            }
            if (dt == 0) o0 = acc; else if (dt == 1) o1 = acc; else if (dt == 2) o2 = acc; else o3 = acc;
        }
        __builtin_amdgcn_s_setprio(0);

        __syncthreads();                 // all waves done reading before next STAGE
    }

    // ---- epilogue: merge k-half wave pairs via LDS, normalize, coalesced store ----
    float* scr = (float*)(smem + qg * 4096);          // [32 d][32 q] f32 per qg
    float* lsp = (float*)(smem + 8192 + qg * 128);    // [32 q] f32 per qg
    if (kh == 1 && hi == 0) lsp[l31] = lrun;
    float inv = 0.f;
    const int qq2 = kh * 16 + (lane >> 2);
    const int dh2 = (lane & 3) * 8;
    #pragma unroll
    for (int dt = 0; dt < 4; ++dt) {
        const f32x16& oo = (dt == 0) ? o0 : (dt == 1) ? o1 : (dt == 2) ? o2 : o3;
        if (kh == 1) {
            #pragma unroll
            for (int r = 0; r < 16; ++r)
                scr[((r & 3) + 8 * (r >> 2) + 4 * hi) * 32 + l31] = oo[r];
        }
        __syncthreads();
        if (kh == 0) {
            if (dt == 0) inv = 1.0f / (lrun + lsp[l31]);
            #pragma unroll
            for (int r = 0; r < 16; ++r) {
                int ix = ((r & 3) + 8 * (r >> 2) + 4 * hi) * 32 + l31;
                scr[ix] = (scr[ix] + oo[r]) * inv;
            }
        }
        __syncthreads();
        float t[8];
        #pragma unroll
        for (int c2 = 0; c2 < 8; ++c2)
            t[c2] = scr[(dh2 + c2) * 32 + qq2];
        float* od = op + (size_t)(qb + qg * 32 + qq2) * Dc + dt * 32 + dh2;
        float4 f4a, f4b;
        f4a.x = t[0]; f4a.y = t[1]; f4a.z = t[2]; f4a.w = t[3];
        f4b.x = t[4]; f4b.y = t[5]; f4b.z = t[6]; f4b.w = t[7];
        *(float4*)(od)     = f4a;
        *(float4*)(od + 4) = f4b;
        if (dt < 3) __syncthreads();
    }
}

extern "C" void kernel_launch(void* const* d_in, const int* in_sizes, int n_in,
                              void* d_out, int out_size, void* d_ws, size_t ws_size,
                              hipStream_t stream) {
    const float* q    = (const float*)d_in[0];
    const float* k    = (const float*)d_in[1];
    const float* v    = (const float*)d_in[2];
    const int*   mask = (const int*)d_in[3];
    float*       out  = (float*)d_out;

    char* ws = (char*)d_ws;
    unsigned short*     kb  = (unsigned short*)(ws + KB_OFF);
    unsigned short*     vt  = (unsigned short*)(ws + VT_OFF);
    unsigned long long* mbp = (unsigned long long*)(ws + MB_OFF);

    hipLaunchKernelGGL(conv_k_kernel, dim3(4096), dim3(256), 0, stream, k, kb);
    hipLaunchKernelGGL(transp_v_kernel, dim3(4, 64, 32), dim3(32, 8), 0, stream, v, vt);
    hipLaunchKernelGGL(mask_pack_kernel, dim3(32768), dim3(256), 0, stream, mask, mbp);

    hipLaunchKernelGGL(rev_attn_kernel, dim3(Lc / QBLK, Bc * Hc), dim3(256), 0, stream,
                       q, kb, vt, mbp, out);
}

// Round 9
// 123.301 us; speedup vs baseline: 1.9788x; 1.2379x over previous
//
#include <hip/hip_runtime.h>
#include <hip/hip_bf16.h>
#include <math.h>

typedef __attribute__((ext_vector_type(8)))  short short8;
typedef __attribute__((ext_vector_type(16))) float f32x16;

#define Bc    2
#define Hc    16
#define Lc    2048
#define Dc    128
#define QBLK  128
#define KBLK  64
#define LOG2E 1.4426950408889634f
#define SCALE 0.08838834764831845f           // 1/sqrt(128)
#define SCL2  (SCALE * LOG2E)                // log2-domain Q scale

// workspace layout
#define KB_OFF   0u
#define KB_BYTES (32u * 2048u * 128u * 2u)
#define VT_OFF   (KB_OFF + KB_BYTES)
#define VT_BYTES (32u * 2048u * 128u * 2u)
#define MB_OFF   (VT_OFF + VT_BYTES)

__device__ __forceinline__ unsigned pk2(float a, float b) {
    unsigned short ua = __builtin_bit_cast(unsigned short, __float2bfloat16(a));
    unsigned short ub = __builtin_bit_cast(unsigned short, __float2bfloat16(b));
    return (unsigned)ua | ((unsigned)ub << 16);
}
__device__ __forceinline__ unsigned short bf16b(float a) {
    return __builtin_bit_cast(unsigned short, __float2bfloat16(a));
}
__device__ __forceinline__ void gload_lds16(const void* g, void* l) {
    __builtin_amdgcn_global_load_lds(
        (const __attribute__((address_space(1))) unsigned int*)g,
        (__attribute__((address_space(3))) unsigned int*)l, 16, 0, 0);
}
__device__ __forceinline__ unsigned cvtpk(float lo, float hi) {
    unsigned r;
    asm("v_cvt_pk_bf16_f32 %0, %1, %2" : "=v"(r) : "v"(lo), "v"(hi));
    return r;
}

// ---- fused prepass: [0,4096) K->bf16 | [4096,12288) V relu+transpose | [12288,14336) mask pack ----
__global__ void prepass_kernel(const float* __restrict__ k, const float* __restrict__ v,
                               const int* __restrict__ mask,
                               unsigned short* __restrict__ kb, unsigned short* __restrict__ vt,
                               unsigned long long* __restrict__ mb) {
    __shared__ float t[32][33];
    int bid = blockIdx.x;
    int tid = threadIdx.x;
    if (bid < 4096) {
        size_t base = ((size_t)bid * 256 + tid) * 8;
        float4 f0 = *(const float4*)(k + base);
        float4 f1 = *(const float4*)(k + base + 4);
        uint4 w;
        w.x = pk2(f0.x, f0.y); w.y = pk2(f0.z, f0.w);
        w.z = pk2(f1.x, f1.y); w.w = pk2(f1.z, f1.w);
        *(uint4*)(kb + base) = w;
    } else if (bid < 12288) {
        int b2 = bid - 4096;
        int bh = b2 >> 8, rem = b2 & 255;
        int l0 = (rem >> 2) * 32, d0 = (rem & 3) * 32;
        int tx = tid & 31, ty = tid >> 5;
        const float* src = v + (size_t)bh * Lc * Dc;
        unsigned short* dst = vt + (size_t)bh * Dc * Lc;
        #pragma unroll
        for (int i = 0; i < 4; ++i) {
            int row = ty * 4 + i;
            t[row][tx] = fmaxf(src[(size_t)(l0 + row) * Dc + d0 + tx], 0.f);
        }
        __syncthreads();
        #pragma unroll
        for (int i = 0; i < 4; ++i) {
            int drow = ty * 4 + i;
            dst[(size_t)(d0 + drow) * Lc + l0 + tx] = bf16b(t[tx][drow]);
        }
    } else {
        int m = bid - 12288;
        int wv = tid >> 6, lane = tid & 63;
        #pragma unroll
        for (int i = 0; i < 16; ++i) {
            int wid = m * 64 + wv * 16 + i;
            int b = wid >> 16, l = (wid >> 5) & 2047, ktw = wid & 31;
            int mm = mask[(((size_t)(b * 2048 + l)) << 11) + ktw * 64 + lane];
            unsigned long long bal = __ballot(mm != 0);
            if (lane == 0) mb[(((size_t)(b * 32 + ktw)) << 11) + l] = bal;
        }
    }
}

// ---- main: 4-wave 32x32 swapped-QK^T, fixed-shift softmax, sm-split PV, counted vmcnt ----
__global__ __launch_bounds__(256, 2) void rev_attn_kernel(
    const float* __restrict__ q,
    const unsigned short* __restrict__ kb,
    const unsigned short* __restrict__ vt,
    const unsigned long long* __restrict__ mb,
    float* __restrict__ out)
{
    // LDS: Kbuf[2] @ 0/16384, Vbuf[2] @ 32768/49152; epilogue scratch aliases base
    __shared__ __align__(16) char smem[65536];

    const int tid  = threadIdx.x;
    const int w    = tid >> 6;          // 0..3
    const int lane = tid & 63;
    const int l31  = lane & 31;
    const int hi   = lane >> 5;
    const int bh   = blockIdx.y;
    const int b    = bh >> 4;
    const int qb   = blockIdx.x * QBLK + w * 32;
    const int qrow = qb + l31;

    const float*              qp = q  + (size_t)bh * Lc * Dc;
    const unsigned short*     kp = kb + (size_t)bh * Lc * Dc;
    const unsigned short*     vp = vt + (size_t)bh * Dc * Lc;
    const unsigned long long* mp = mb + ((size_t)b << 16);       // [32 ktw][2048 l]
    float*                    op = out + (size_t)bh * Lc * Dc;

    // ---- Q B-frags (log2-domain pre-scale): lane holds Q[qrow][c*16 + hi*8 + j] ----
    short8 qf[8];
    {
        const float* qr0 = qp + (size_t)qrow * Dc + hi * 8;
        #pragma unroll
        for (int c = 0; c < 8; ++c) {
            const float* src = qr0 + c * 16;
            #pragma unroll
            for (int j = 0; j < 8; ++j)
                qf[c][j] = (short)bf16b(src[j] * SCL2);
        }
    }

    f32x16 o0 = (f32x16)0.f, o1 = (f32x16)0.f, o2 = (f32x16)0.f, o3 = (f32x16)0.f;
    f32x16 lacc = (f32x16)0.f;          // denominator via MFMA(ones, P)
    short8 ones;
    #pragma unroll
    for (int j = 0; j < 8; ++j) ones[j] = (short)0x3F80;   // bf16 1.0

    // ---- staging (R3-verified both-sides pair) ----
    #define STAGE(buf, kt_) do {                                                   \
        char* Kdst = smem + (buf) * 16384;                                         \
        char* Vdst = smem + 32768 + (buf) * 16384;                                 \
        _Pragma("unroll")                                                          \
        for (int p = 0; p < 4; ++p) {                                              \
            int l   = p * 256 + tid;                                               \
            int row = l >> 4, cl = l & 15;                                         \
            int s_  = cl ^ (row & 15);                                             \
            gload_lds16(kp + (size_t)((kt_) + row) * Dc + s_ * 8, Kdst + l * 16);  \
            int ds_ = row + ((s_ >> 3) << 6);                                      \
            int ko_ = (s_ & 7) * 8;                                                \
            gload_lds16(vp + (size_t)ds_ * Lc + (kt_) + ko_, Vdst + l * 16);       \
        }                                                                          \
    } while (0)

    // slice: 8 elems of SV -> masked exp2 -> packed bf16 A-frag (cvt_pk + permlane32_swap)
    #define MK_SLICE(PA, SV, J0, CS0, MREG) do {                                   \
        float e0 = ((MREG >> (CS0 + 0)) & 1u)  ? exp2f(SV[J0 + 0]) : 0.f;          \
        float e1 = ((MREG >> (CS0 + 1)) & 1u)  ? exp2f(SV[J0 + 1]) : 0.f;          \
        float e2 = ((MREG >> (CS0 + 2)) & 1u)  ? exp2f(SV[J0 + 2]) : 0.f;          \
        float e3 = ((MREG >> (CS0 + 3)) & 1u)  ? exp2f(SV[J0 + 3]) : 0.f;          \
        float e4 = ((MREG >> (CS0 + 8)) & 1u)  ? exp2f(SV[J0 + 4]) : 0.f;          \
        float e5 = ((MREG >> (CS0 + 9)) & 1u)  ? exp2f(SV[J0 + 5]) : 0.f;          \
        float e6 = ((MREG >> (CS0 + 10)) & 1u) ? exp2f(SV[J0 + 6]) : 0.f;          \
        float e7 = ((MREG >> (CS0 + 11)) & 1u) ? exp2f(SV[J0 + 7]) : 0.f;          \
        unsigned a_ = cvtpk(e0, e1), a2_ = cvtpk(e2, e3);                          \
        unsigned b_ = cvtpk(e4, e5), b2_ = cvtpk(e6, e7);                          \
        asm volatile("v_permlane32_swap_b32 %0, %1" : "+v"(a_),  "+v"(b_));        \
        asm volatile("v_permlane32_swap_b32 %0, %1" : "+v"(a2_), "+v"(b2_));       \
        union { unsigned u[4]; short8 v8; } tu_;                                   \
        tu_.u[0] = a_; tu_.u[1] = a2_; tu_.u[2] = b_; tu_.u[3] = b2_;              \
        PA = tu_.v8;                                                               \
    } while (0)

    // PV for one k-slice: lacc + 4 d-tiles
    #define PV_SLICE(PA, KS) do {                                                  \
        __builtin_amdgcn_s_setprio(1);                                             \
        lacc = __builtin_amdgcn_mfma_f32_32x32x16_bf16(ones, PA, lacc, 0, 0, 0);   \
        short8 vfa = *(const short8*)(Vb + vrowA * 256 + ((((0 << 3) | ((KS) << 1) | hi) ^ vswz) * 16)); \
        o0 = __builtin_amdgcn_mfma_f32_32x32x16_bf16(vfa, PA, o0, 0, 0, 0);        \
        short8 vfb = *(const short8*)(Vb + vrowB * 256 + ((((0 << 3) | ((KS) << 1) | hi) ^ vswz) * 16)); \
        o1 = __builtin_amdgcn_mfma_f32_32x32x16_bf16(vfb, PA, o1, 0, 0, 0);        \
        short8 vfc = *(const short8*)(Vb + vrowA * 256 + ((((1 << 3) | ((KS) << 1) | hi) ^ vswz) * 16)); \
        o2 = __builtin_amdgcn_mfma_f32_32x32x16_bf16(vfc, PA, o2, 0, 0, 0);        \
        short8 vfd = *(const short8*)(Vb + vrowB * 256 + ((((1 << 3) | ((KS) << 1) | hi) ^ vswz) * 16)); \
        o3 = __builtin_amdgcn_mfma_f32_32x32x16_bf16(vfd, PA, o3, 0, 0, 0);        \
        __builtin_amdgcn_s_setprio(0);                                             \
    } while (0)

    const int vrowA = l31;
    const int vrowB = 32 + l31;
    const int vswz  = l31 & 15;

    int cur = 0;
    STAGE(0, 0);
    asm volatile("s_waitcnt vmcnt(0)" ::: "memory");
    __builtin_amdgcn_s_barrier();
    __builtin_amdgcn_sched_barrier(0);

    for (int kt = 0; kt < Lc; kt += KBLK) {
        // prefetch next tile (wrap on last iter keeps the vmcnt count uniform)
        STAGE(cur ^ 1, (kt + KBLK) & (Lc - 1));
        unsigned long long mw = mp[((size_t)(kt >> 6) << 11) + qrow];

        // cur buffer ready: my prior-iter 8 stage loads done; 8 new + 1 mask may remain
        asm volatile("s_waitcnt vmcnt(9)" ::: "memory");
        __builtin_amdgcn_s_barrier();
        __builtin_amdgcn_sched_barrier(0);

        const char* Kb = smem + cur * 16384;
        const char* Vb = smem + 32768 + cur * 16384;

        // ---- QK^T (swapped): S^T[k][q], col=q=l31 ----
        f32x16 s0 = (f32x16)0.f, s1 = (f32x16)0.f;
        __builtin_amdgcn_s_setprio(1);
        #pragma unroll
        for (int c = 0; c < 8; ++c) {
            int r0 = l31;
            short8 kf0 = *(const short8*)(Kb + r0 * 256 + ((((c << 1) | hi)) ^ (r0 & 15)) * 16);
            s0 = __builtin_amdgcn_mfma_f32_32x32x16_bf16(kf0, qf[c], s0, 0, 0, 0);
            int r1 = 32 + l31;
            short8 kf1 = *(const short8*)(Kb + r1 * 256 + ((((c << 1) | hi)) ^ (r1 & 15)) * 16);
            s1 = __builtin_amdgcn_mfma_f32_32x32x16_bf16(kf1, qf[c], s1, 0, 0, 0);
        }
        __builtin_amdgcn_s_setprio(0);

        unsigned m0 = ((unsigned)(mw & 0xffffffffull)) >> (4 * hi);
        unsigned m1 = ((unsigned)(mw >> 32)) >> (4 * hi);

        // ---- sm-split: per k-slice {softmax 8 elems} then {5 MFMAs} ----
        short8 pa;
        MK_SLICE(pa, s0, 0, 0,  m0);  PV_SLICE(pa, 0);
        MK_SLICE(pa, s0, 8, 16, m0);  PV_SLICE(pa, 1);
        MK_SLICE(pa, s1, 0, 0,  m1);  PV_SLICE(pa, 2);
        MK_SLICE(pa, s1, 8, 16, m1);  PV_SLICE(pa, 3);

        // all reads of cur done before next iter's STAGE overwrites it
        asm volatile("" ::: "memory");
        __builtin_amdgcn_s_barrier();
        __builtin_amdgcn_sched_barrier(0);
        cur ^= 1;
    }

    // ---- epilogue: O^T -> LDS transpose -> coalesced float4 stores ----
    __syncthreads();
    float inv = 1.0f / lacc[0];         // all regs identical (A = ones); col=q=l31
    float* scr = (float*)(smem + w * 4608);
    const int qq = lane >> 1;
    const int dh = (lane & 1) * 16;
    #pragma unroll
    for (int dt = 0; dt < 4; ++dt) {
        const f32x16& oo = (dt == 0) ? o0 : (dt == 1) ? o1 : (dt == 2) ? o2 : o3;
        #pragma unroll
        for (int r = 0; r < 16; ++r) {
            int drow = (r & 3) + 8 * (r >> 2) + 4 * hi;
            scr[drow * 36 + l31] = oo[r] * inv;
        }
        asm volatile("s_waitcnt lgkmcnt(0)" ::: "memory");
        __builtin_amdgcn_sched_barrier(0);
        float t[16];
        #pragma unroll
        for (int c2 = 0; c2 < 16; ++c2)
            t[c2] = scr[(dh + c2) * 36 + qq];
        asm volatile("s_waitcnt lgkmcnt(0)" ::: "memory");
        __builtin_amdgcn_sched_barrier(0);
        float* od = op + (size_t)(qb + qq) * Dc + dt * 32 + dh;
        #pragma unroll
        for (int c2 = 0; c2 < 4; ++c2) {
            float4 f4; f4.x = t[c2*4]; f4.y = t[c2*4+1]; f4.z = t[c2*4+2]; f4.w = t[c2*4+3];
            *(float4*)(od + c2 * 4) = f4;
        }
    }
}

extern "C" void kernel_launch(void* const* d_in, const int* in_sizes, int n_in,
                              void* d_out, int out_size, void* d_ws, size_t ws_size,
                              hipStream_t stream) {
    const float* q    = (const float*)d_in[0];
    const float* k    = (const float*)d_in[1];
    const float* v    = (const float*)d_in[2];
    const int*   mask = (const int*)d_in[3];
    float*       out  = (float*)d_out;

    char* ws = (char*)d_ws;
    unsigned short*     kb  = (unsigned short*)(ws + KB_OFF);
    unsigned short*     vt  = (unsigned short*)(ws + VT_OFF);
    unsigned long long* mbp = (unsigned long long*)(ws + MB_OFF);

    hipLaunchKernelGGL(prepass_kernel, dim3(14336), dim3(256), 0, stream, k, v, mask, kb, vt, mbp);
    hipLaunchKernelGGL(rev_attn_kernel, dim3(Lc / QBLK, Bc * Hc), dim3(256), 0, stream,
                       q, kb, vt, mbp, out);
}